// Round 4
// baseline (1881.592 us; speedup 1.0000x reference)
//
#include <hip/hip_runtime.h>

// NLCE: non-local (channel attention) + Deep-TEN encoding, B=8 C=512 C1=256 D=128 K=32 N=9216.
// All inputs/outputs fp32 (reference is jnp.float32; the "bf16" in the test label is
// hard-coded text). Internal compute fp32.
// Algebra: z = (W2 f Wg + I) X + q 1^T with f = softmax(Wth G Wph^T + bias terms), G = X X^T.
// z lives in d_out (fp32). Workspace (aliased): 14.2 MB base + zq (fp32 36 MB, or bf16 18 MB
// fallback if ws_size is small).

typedef unsigned short u16;

#define Bb 8
#define Cc 512
#define C1 256
#define Dd 128
#define Kk 32
#define Nn 9216

__device__ __forceinline__ float b2f(u16 u) {
  union { unsigned int i; float f; } v; v.i = ((unsigned int)u) << 16; return v.f;
}
__device__ __forceinline__ u16 f2b(float f) {
  union { float f; unsigned int i; } v; v.f = f;
  unsigned int x = v.i;
  return (u16)((x + 0x7fffu + ((x >> 16) & 1u)) >> 16);  // RNE
}

__device__ __forceinline__ float b2fOrF(float x) { return x; }
__device__ __forceinline__ float b2fOrF(u16 x) { return b2f(x); }

__device__ __forceinline__ float4 load4(const float* p) { return *(const float4*)p; }
__device__ __forceinline__ float4 load4(const u16* p) {
  ushort4 q = *(const ushort4*)p;
  return make_float4(b2f(q.x), b2f(q.y), b2f(q.z), b2f(q.w));
}
__device__ __forceinline__ void store4(float* p, float a, float b, float c, float d) {
  *(float4*)p = make_float4(a, b, c, d);
}
__device__ __forceinline__ void store4(u16* p, float a, float b, float c, float d) {
  ushort4 q; q.x = f2b(a); q.y = f2b(b); q.z = f2b(c); q.w = f2b(d);
  *(ushort4*)p = q;
}

__device__ __forceinline__ float waveSum(float v) {
  #pragma unroll
  for (int o = 32; o > 0; o >>= 1) v += __shfl_xor(v, o);
  return v;
}
__device__ __forceinline__ float waveMax(float v) {
  #pragma unroll
  for (int o = 32; o > 0; o >>= 1) v = fmaxf(v, __shfl_xor(v, o));
  return v;
}
__device__ __forceinline__ float blockSum256(float v) {
  __shared__ float sm[4];
  v = waveSum(v);
  if ((threadIdx.x & 63) == 0) sm[threadIdx.x >> 6] = v;
  __syncthreads();
  float r = sm[0] + sm[1] + sm[2] + sm[3];
  __syncthreads();
  return r;
}
__device__ __forceinline__ float blockMax256(float v) {
  __shared__ float sm[4];
  v = waveMax(v);
  if ((threadIdx.x & 63) == 0) sm[threadIdx.x >> 6] = v;
  __syncthreads();
  float r = fmaxf(fmaxf(sm[0], sm[1]), fmaxf(sm[2], sm[3]));
  __syncthreads();
  return r;
}

// ---------------- generic 64x64 tiled GEMM, fp32 accumulate ----------------
// C[b] = A[b] @ B[b] (+ biasRow per-M) (+ addMat fp32 elementwise)
// A: M x K row-major. B: (TRANSB ? N x K : K x N) row-major. M,N %64==0, K %16==0.
template<typename TA, typename TB, typename TO, bool TRANSB>
__global__ __launch_bounds__(256) void gemm64(
    const TA* __restrict__ A, const TB* __restrict__ B, TO* __restrict__ C,
    int M, int N, int K,
    long long sA, long long sB, long long sC,
    const float* __restrict__ addMat, long long sAdd,
    const float* __restrict__ biasRow, long long sBias)
{
  const int bz = blockIdx.z;
  A += (long long)bz * sA;
  B += (long long)bz * sB;
  C += (long long)bz * sC;
  const int m0 = blockIdx.y * 64, n0 = blockIdx.x * 64;
  __shared__ __align__(16) float As[16][64];
  __shared__ __align__(16) float Bs[16][64];
  const int t = threadIdx.x;
  const int lr = t >> 2, lk = (t & 3) << 2;
  const int tm = (t >> 4) << 2, tn = (t & 15) << 2;
  float acc[4][4] = {};
  for (int k0 = 0; k0 < K; k0 += 16) {
    {
      float4 a = load4(A + (long long)(m0 + lr) * K + (k0 + lk));
      As[lk + 0][lr] = a.x; As[lk + 1][lr] = a.y; As[lk + 2][lr] = a.z; As[lk + 3][lr] = a.w;
    }
    if (TRANSB) {
      float4 b = load4(B + (long long)(n0 + lr) * K + (k0 + lk));
      Bs[lk + 0][lr] = b.x; Bs[lk + 1][lr] = b.y; Bs[lk + 2][lr] = b.z; Bs[lk + 3][lr] = b.w;
    } else {
      const int kr = t >> 4, nc = (t & 15) << 2;
      float4 b = load4(B + (long long)(k0 + kr) * N + (n0 + nc));
      *(float4*)&Bs[kr][nc] = b;
    }
    __syncthreads();
    #pragma unroll
    for (int kk = 0; kk < 16; ++kk) {
      const float4 av = *(const float4*)&As[kk][tm];
      const float4 bv = *(const float4*)&Bs[kk][tn];
      acc[0][0] = fmaf(av.x, bv.x, acc[0][0]);
      acc[0][1] = fmaf(av.x, bv.y, acc[0][1]);
      acc[0][2] = fmaf(av.x, bv.z, acc[0][2]);
      acc[0][3] = fmaf(av.x, bv.w, acc[0][3]);
      acc[1][0] = fmaf(av.y, bv.x, acc[1][0]);
      acc[1][1] = fmaf(av.y, bv.y, acc[1][1]);
      acc[1][2] = fmaf(av.y, bv.z, acc[1][2]);
      acc[1][3] = fmaf(av.y, bv.w, acc[1][3]);
      acc[2][0] = fmaf(av.z, bv.x, acc[2][0]);
      acc[2][1] = fmaf(av.z, bv.y, acc[2][1]);
      acc[2][2] = fmaf(av.z, bv.z, acc[2][2]);
      acc[2][3] = fmaf(av.z, bv.w, acc[2][3]);
      acc[3][0] = fmaf(av.w, bv.x, acc[3][0]);
      acc[3][1] = fmaf(av.w, bv.y, acc[3][1]);
      acc[3][2] = fmaf(av.w, bv.z, acc[3][2]);
      acc[3][3] = fmaf(av.w, bv.w, acc[3][3]);
    }
    __syncthreads();
  }
  #pragma unroll
  for (int i = 0; i < 4; ++i) {
    const int m = m0 + tm + i;
    float bias = biasRow ? biasRow[bz * sBias + m] : 0.f;
    float v0 = acc[i][0] + bias, v1 = acc[i][1] + bias;
    float v2 = acc[i][2] + bias, v3 = acc[i][3] + bias;
    if (addMat) {
      const float* ap = addMat + bz * sAdd + (long long)m * N + (n0 + tn);
      float4 a4 = load4(ap);
      v0 += a4.x; v1 += a4.y; v2 += a4.z; v3 += a4.w;
    }
    store4(C + (long long)m * N + (n0 + tn), v0, v1, v2, v3);
  }
}

// ---------------- small kernels ----------------
__global__ __launch_bounds__(256) void rowsum_kernel(const float* __restrict__ X,
                                                     float* __restrict__ s, int N) {
  long long row = blockIdx.x;
  const float* p = X + row * N;
  float acc = 0.f;
  for (int i = threadIdx.x; i < N; i += 256) acc += p[i];
  acc = blockSum256(acc);
  if (threadIdx.x == 0) s[row] = acc;
}

// u[b,i] = sum_k W[i,k]*s[b,k]   (W: 256x512 fp32)
__global__ __launch_bounds__(256) void gemv512_kernel(const float* __restrict__ W,
                                                      const float* __restrict__ s,
                                                      float* __restrict__ out) {
  int b = blockIdx.x;
  __shared__ float ssm[Cc];
  for (int i = threadIdx.x; i < Cc; i += 256) ssm[i] = s[b * Cc + i];
  __syncthreads();
  int i = threadIdx.x;
  const float* wr = W + i * Cc;
  float acc = 0.f;
  for (int k = 0; k < Cc; ++k) acc = fmaf(wr[k], ssm[k], acc);
  out[b * C1 + i] = acc;
}

// in-place row softmax of L (B*C1 rows of C1), with bias terms
__global__ __launch_bounds__(256) void softmax_kernel(float* __restrict__ L,
    const float* __restrict__ bth, const float* __restrict__ bph,
    const float* __restrict__ u, const float* __restrict__ v) {
  int row = blockIdx.x;                 // b*256 + i
  int b = row >> 8, i = row & 255;
  int j = threadIdx.x;
  float bt = bth[i], bp = bph[j];
  long long idx = (long long)row * C1 + j;
  float val = L[idx] + bt * v[b * C1 + j] + u[b * C1 + i] * bp + (float)Nn * bt * bp;
  float mx = blockMax256(val);
  float p = expf(val - mx);
  float sm = blockSum256(p);
  L[idx] = p / sm;
}

// w[b,i] = sum_j f[b,i,j] * b_g[j]
__global__ __launch_bounds__(256) void w_kernel(const float* __restrict__ f,
                                                const float* __restrict__ bg,
                                                float* __restrict__ w) {
  int b = blockIdx.x;
  __shared__ float bgs[C1];
  bgs[threadIdx.x] = bg[threadIdx.x];
  __syncthreads();
  int i = threadIdx.x;
  const float* fr = f + ((long long)b * C1 + i) * C1;
  float acc = 0.f;
  for (int j = 0; j < C1; ++j) acc = fmaf(fr[j], bgs[j], acc);
  w[b * C1 + i] = acc;
}

// q[b,c] = b2[c] + sum_i W2[c,i]*w[b,i]
__global__ __launch_bounds__(256) void q_kernel(const float* __restrict__ W2,
                                                const float* __restrict__ b2v,
                                                const float* __restrict__ w,
                                                float* __restrict__ q) {
  int gi = blockIdx.x * 256 + threadIdx.x;
  int b = gi >> 9, c = gi & 511;
  __shared__ float wsm[C1];
  wsm[threadIdx.x] = w[b * C1 + threadIdx.x];
  __syncthreads();
  const float* wr = W2 + c * C1;
  float acc = b2v[c];
  for (int i = 0; i < C1; ++i) acc = fmaf(wr[i], wsm[i], acc);
  q[gi] = acc;
}

// Fused encoder: per 256-pixel tile, compute soft-assign A (softmax over K of
// scale*dist), accumulate Asum[b,k] and Eraw[b,k,d] += sum_n A*x via atomics.
template<typename ZT>
__global__ __launch_bounds__(256) void enc_kernel(
    const ZT* __restrict__ zq,      // [B][D][N]
    const float* __restrict__ cw,   // [K][D]
    const float* __restrict__ sc,   // [K]
    float* __restrict__ Eraw,       // [B][K][D] pre-zeroed
    float* __restrict__ Asum)       // [B][K]    pre-zeroed
{
  __shared__ float csm[Kk][Dd + 1];     // 16.5 KB
  __shared__ float cc[Kk], ssm[Kk];
  __shared__ float sA[Kk][256 + 1];     // 32.9 KB  A^T
  __shared__ float zs[Dd][17];          // 8.7 KB   staged x for pass2
  const int tid = threadIdx.x;
  const int b = blockIdx.y;
  const int n0 = blockIdx.x * 256;

  #pragma unroll
  for (int r = 0; r < 16; ++r) {
    int idx = r * 256 + tid;
    csm[idx >> 7][idx & 127] = cw[idx];
  }
  if (tid < Kk) ssm[tid] = sc[tid];
  __syncthreads();
  if (tid < Kk) {
    float a = 0.f;
    for (int d = 0; d < Dd; ++d) { float cv = csm[tid][d]; a = fmaf(cv, cv, a); }
    cc[tid] = a;
  }
  __syncthreads();

  // pass 1: one pixel per thread
  const int n = n0 + tid;
  const ZT* zp = zq + (long long)b * Dd * Nn + n;
  float dots[Kk];
  #pragma unroll
  for (int k = 0; k < Kk; ++k) dots[k] = 0.f;
  float xx = 0.f;
  for (int d = 0; d < Dd; ++d) {
    float xv = b2fOrF(zp[(long long)d * Nn]);
    xx = fmaf(xv, xv, xx);
    #pragma unroll
    for (int k = 0; k < Kk; ++k) dots[k] = fmaf(csm[k][d], xv, dots[k]);
  }
  float mx = -1e30f;
  #pragma unroll
  for (int k = 0; k < Kk; ++k) {
    float l = ssm[k] * (xx - 2.f * dots[k] + cc[k]);
    dots[k] = l;
    mx = fmaxf(mx, l);
  }
  float sum = 0.f;
  #pragma unroll
  for (int k = 0; k < Kk; ++k) { float p = expf(dots[k] - mx); dots[k] = p; sum += p; }
  float inv = 1.f / sum;
  #pragma unroll
  for (int k = 0; k < Kk; ++k) sA[k][tid] = dots[k] * inv;
  __syncthreads();
  if (tid < Kk) {
    float s = 0.f;
    for (int p = 0; p < 256; ++p) s += sA[tid][p];
    atomicAdd(&Asum[b * Kk + tid], s);
  }

  // pass 2: E_part[k][d0..d0+15] over this tile's 256 pixels (16 px per stage)
  float acc[16];
  #pragma unroll
  for (int j = 0; j < 16; ++j) acc[j] = 0.f;
  const int k = tid & 31, d0 = (tid >> 5) * 16;
  const int ldd = tid >> 1, lpx = (tid & 1) * 8;
  for (int it = 0; it < 16; ++it) {
    __syncthreads();
    {
      const ZT* src = zq + ((long long)b * Dd + ldd) * Nn + n0 + it * 16 + lpx;
      float4 a4 = load4(src);
      float4 b4 = load4(src + 4);
      zs[ldd][lpx + 0] = a4.x; zs[ldd][lpx + 1] = a4.y;
      zs[ldd][lpx + 2] = a4.z; zs[ldd][lpx + 3] = a4.w;
      zs[ldd][lpx + 4] = b4.x; zs[ldd][lpx + 5] = b4.y;
      zs[ldd][lpx + 6] = b4.z; zs[ldd][lpx + 7] = b4.w;
    }
    __syncthreads();
    #pragma unroll
    for (int p = 0; p < 16; ++p) {
      float a = sA[k][it * 16 + p];
      #pragma unroll
      for (int j = 0; j < 16; ++j) acc[j] = fmaf(a, zs[d0 + j][p], acc[j]);
    }
  }
  float* Ep = Eraw + ((long long)b * Kk + k) * Dd + d0;
  #pragma unroll
  for (int j = 0; j < 16; ++j) atomicAdd(Ep + j, acc[j]);
}

// per-k BN over (b,d), relu, Es[b,d] += e
__global__ __launch_bounds__(256) void bn_kernel(const float* __restrict__ Eraw,
    const float* __restrict__ Asum, const float* __restrict__ cw, float* __restrict__ Es) {
  int k = blockIdx.x, tid = threadIdx.x;
  float vals[4], s = 0.f, s2 = 0.f;
  #pragma unroll
  for (int r = 0; r < 4; ++r) {
    int i = r * 256 + tid;
    int b = i >> 7, d = i & 127;
    float e = Eraw[((long long)b * Kk + k) * Dd + d] - Asum[b * Kk + k] * cw[k * Dd + d];
    vals[r] = e; s += e; s2 = fmaf(e, e, s2);
  }
  s = blockSum256(s);
  s2 = blockSum256(s2);
  float mean = s * (1.f / 1024.f);
  float var = fmaxf(s2 * (1.f / 1024.f) - mean * mean, 0.f);
  float rs = rsqrtf(var + 1e-5f);
  #pragma unroll
  for (int r = 0; r < 4; ++r) {
    int i = r * 256 + tid;
    int b = i >> 7, d = i & 127;
    float e = (vals[r] - mean) * rs;
    if (e > 0.f) atomicAdd(&Es[b * Dd + d], e);
  }
}

// gamma[b,c] = sigmoid(b_fc[c] + sum_d W_fc[c,d]*Es[b,d])
__global__ __launch_bounds__(256) void gamma_kernel(const float* __restrict__ Es,
    const float* __restrict__ Wfc, const float* __restrict__ bfc, float* __restrict__ gam) {
  int gi = blockIdx.x * 256 + threadIdx.x;
  int b = gi >> 9, c = gi & 511;
  __shared__ float esm[Dd];
  if (threadIdx.x < Dd) esm[threadIdx.x] = Es[b * Dd + threadIdx.x];
  __syncthreads();
  const float* wr = Wfc + c * Dd;
  float acc = bfc[c];
  for (int d = 0; d < Dd; ++d) acc = fmaf(wr[d], esm[d], acc);
  gam[gi] = 1.f / (1.f + expf(-acc));
}

__global__ __launch_bounds__(256) void scaleout_f32(float* __restrict__ out,
    const float* __restrict__ gam) {
  unsigned int idx = blockIdx.x * 256u + threadIdx.x;
  unsigned int f = idx * 4u;
  unsigned int bc = f / (unsigned)Nn;
  float g = gam[bc];
  float4 zv = *(const float4*)(out + f);
  store4(out + f, zv.x * g, zv.y * g, zv.z * g, zv.w * g);
}

// ---------------- host launcher ----------------
extern "C" void kernel_launch(void* const* d_in, const int* in_sizes, int n_in,
                              void* d_out, int out_size, void* d_ws, size_t ws_size,
                              hipStream_t stream) {
  const float* X   = (const float*)d_in[0];
  const float* Wth = (const float*)d_in[1];
  const float* bth = (const float*)d_in[2];
  const float* Wph = (const float*)d_in[3];
  const float* bph = (const float*)d_in[4];
  const float* Wg  = (const float*)d_in[5];
  const float* bg  = (const float*)d_in[6];
  const float* W2  = (const float*)d_in[7];
  const float* b2v = (const float*)d_in[8];
  const float* W3  = (const float*)d_in[9];
  const float* b3v = (const float*)d_in[10];
  const float* CW  = (const float*)d_in[11];
  const float* SC  = (const float*)d_in[12];
  const float* Wfc = (const float*)d_in[13];
  const float* bfc = (const float*)d_in[14];
  float* out = (float*)d_out;
  float* wsf = (float*)d_ws;

  // workspace layout (floats), lifetime-aliased
  const long long szL   = (long long)Bb * C1 * C1;   // 524288   (f)
  const long long szRA  = (long long)Bb * Cc * Cc;   // 2097152  (G then P)
  const long long szRB  = (long long)Bb * C1 * Cc;   // 1048576  (U then Mm)
  long long off = 0;
  float* s_   = wsf + off; off += Bb * Cc;
  float* u_   = wsf + off; off += Bb * C1;
  float* v_   = wsf + off; off += Bb * C1;
  float* w_   = wsf + off; off += Bb * C1;
  float* q_   = wsf + off; off += Bb * Cc;
  float* Eraw_= wsf + off; off += (long long)Bb * Kk * Dd;  // contiguous: memset'd together
  float* Es_  = wsf + off; off += Bb * Dd;
  float* Asum_= wsf + off; off += Bb * Kk;
  float* gam_ = wsf + off; off += Bb * Cc;
  float* L_   = wsf + off; off += szL;
  float* regA = wsf + off; off += szRA;
  float* regB = wsf + off; off += szRB;
  const long long baseFloats = off;
  float* zqf  = wsf + off;                 // fp32 zq tier
  u16*   zqh  = (u16*)(wsf + off);         // bf16 zq tier (same offset)
  const size_t needF32 = (size_t)(baseFloats + (long long)Bb * Dd * Nn) * 4;
  const bool zqIsF32 = ws_size >= needF32;

  const long long strX = (long long)Cc * Nn;
  const long long sG = (long long)Cc * Cc;
  const long long sU = (long long)C1 * Cc;
  const long long sL = (long long)C1 * C1;

  rowsum_kernel<<<Bb * Cc, 256, 0, stream>>>(X, s_, Nn);
  // G = X X^T  -> regA
  gemm64<float, float, float, true><<<dim3(8, 8, Bb), 256, 0, stream>>>(
      X, X, regA, Cc, Cc, Nn, strX, strX, sG, nullptr, 0, nullptr, 0);
  // U = Wth @ G -> regB
  gemm64<float, float, float, false><<<dim3(8, 4, Bb), 256, 0, stream>>>(
      Wth, regA, regB, C1, Cc, Cc, 0, sG, sU, nullptr, 0, nullptr, 0);
  gemv512_kernel<<<Bb, 256, 0, stream>>>(Wth, s_, u_);
  gemv512_kernel<<<Bb, 256, 0, stream>>>(Wph, s_, v_);
  // L = U @ Wph^T
  gemm64<float, float, float, true><<<dim3(4, 4, Bb), 256, 0, stream>>>(
      regB, Wph, L_, C1, C1, Cc, sU, 0, sL, nullptr, 0, nullptr, 0);
  softmax_kernel<<<Bb * C1, 256, 0, stream>>>(L_, bth, bph, u_, v_);
  w_kernel<<<Bb, 256, 0, stream>>>(L_, bg, w_);
  // Mm = f @ Wg -> regB (U dead)
  gemm64<float, float, float, false><<<dim3(8, 4, Bb), 256, 0, stream>>>(
      L_, Wg, regB, C1, Cc, C1, sL, 0, sU, nullptr, 0, nullptr, 0);
  q_kernel<<<16, 256, 0, stream>>>(W2, b2v, w_, q_);
  // P = W2 @ Mm -> regA (G dead)
  gemm64<float, float, float, false><<<dim3(8, 8, Bb), 256, 0, stream>>>(
      W2, regB, regA, Cc, Cc, C1, 0, sU, sG, nullptr, 0, nullptr, 0);
  // z = P @ X + X + q  -> out (fp32)
  gemm64<float, float, float, false><<<dim3(144, 8, Bb), 256, 0, stream>>>(
      regA, X, out, Cc, Nn, Cc, sG, strX, strX, X, strX, q_, Cc);
  // zq = W3 @ z + b3
  hipMemsetAsync(Eraw_, 0, (size_t)(Bb * Kk * Dd + Bb * Dd + Bb * Kk) * 4, stream);
  if (zqIsF32) {
    gemm64<float, float, float, false><<<dim3(144, 2, Bb), 256, 0, stream>>>(
        W3, out, zqf, Dd, Nn, Cc, 0, strX, (long long)Dd * Nn, nullptr, 0, b3v, 0);
    enc_kernel<float><<<dim3(36, Bb), 256, 0, stream>>>(zqf, CW, SC, Eraw_, Asum_);
  } else {
    gemm64<float, float, u16, false><<<dim3(144, 2, Bb), 256, 0, stream>>>(
        W3, out, zqh, Dd, Nn, Cc, 0, strX, (long long)Dd * Nn, nullptr, 0, b3v, 0);
    enc_kernel<u16><<<dim3(36, Bb), 256, 0, stream>>>(zqh, CW, SC, Eraw_, Asum_);
  }
  bn_kernel<<<Kk, 256, 0, stream>>>(Eraw_, Asum_, CW, Es_);
  gamma_kernel<<<16, 256, 0, stream>>>(Es_, Wfc, bfc, gam_);
  const unsigned int n4 = (unsigned)(Bb * Cc * Nn / 4);
  scaleout_f32<<<n4 / 256, 256, 0, stream>>>(out, gam_);
  (void)in_sizes; (void)n_in; (void)out_size;
}